// Round 2
// baseline (322.515 us; speedup 1.0000x reference)
//
#include <hip/hip_runtime.h>
#include <hip/hip_bf16.h>
#include <math.h>

#define NB   1024    // number of key blocks per (b)
#define HKH  8       // Hk
#define DGD  128     // Dg
// k: (4, 65536, 8, 128) fp32; block segment per (b,blk): 64*8*128 floats = 65536 floats

// ---------------- Kernel A: pooling (mean||max over 64 rows) ----------------
// grid = B*NB = 4096 blocks, 256 threads. Each block reads a contiguous 256KB
// segment of k and writes pooled[b,blk,h,0:128]=mean, [128:256]=max.
__global__ __launch_bounds__(256) void pool_kernel(const float* __restrict__ kin,
                                                   float* __restrict__ pooled) {
    int blkid = blockIdx.x;            // b*NB + blk
    int t = threadIdx.x;               // 0..255 -> float4 index within 1024-float row
    const float4* src = (const float4*)kin + (size_t)blkid * 16384 + t;
    float4 v = src[0];
    float sx = v.x, sy = v.y, sz = v.z, sw = v.w;
    float mx = v.x, my = v.y, mz = v.z, mw = v.w;
#pragma unroll 8
    for (int r = 1; r < 64; ++r) {
        float4 u = src[(size_t)r * 256];
        sx += u.x; sy += u.y; sz += u.z; sw += u.w;
        mx = fmaxf(mx, u.x); my = fmaxf(my, u.y);
        mz = fmaxf(mz, u.z); mw = fmaxf(mw, u.w);
    }
    int h = t >> 5;                // 32 float4 per head
    int d = (t & 31) << 2;
    float* dst = pooled + ((size_t)blkid * HKH + h) * 256 + d;
    const float inv = 1.0f / 64.0f;
    *(float4*)dst         = make_float4(sx * inv, sy * inv, sz * inv, sw * inv);
    *(float4*)(dst + 128) = make_float4(mx, my, mz, mw);
}

// ---------------- Kernel Q: query gate projection -----------------
// grid = B*HK = 32 blocks, 128 threads (thread = output dim o).
// qp[b,h,o] = sum_{g,i} q[b,0,h*4+g,i] * Wq[h,g,i,o]; RMSNorm; RoPE.
__global__ __launch_bounds__(128) void qproj_kernel(const float* __restrict__ q,
                                                    const float* __restrict__ Wq,
                                                    const float* __restrict__ qnw,
                                                    const float* __restrict__ cq,
                                                    const float* __restrict__ sq,
                                                    float* __restrict__ qv) {
    int b = blockIdx.x >> 3, h = blockIdx.x & 7;
    int o = threadIdx.x;
    __shared__ float qs[512];
    __shared__ float red[2];
    __shared__ float ybuf[128];
    for (int idx = o; idx < 512; idx += 128)
        qs[idx] = q[(size_t)b * 4096 + (size_t)h * 512 + idx];
    __syncthreads();
    const float* wqp = Wq + (size_t)h * 512 * 128 + o;
    float acc = 0.0f;
#pragma unroll 4
    for (int gi = 0; gi < 512; ++gi)
        acc = fmaf(qs[gi], wqp[(size_t)gi * 128], acc);
    // RMSNorm over o (128)
    float ss = acc * acc;
    for (int off = 32; off > 0; off >>= 1) ss += __shfl_xor(ss, off);
    if ((o & 63) == 0) red[o >> 6] = ss;
    __syncthreads();
    float tot = red[0] + red[1];
    float scale = rsqrtf(tot * (1.0f / 128.0f) + 1e-6f);
    float y = acc * scale * qnw[o];
    ybuf[o] = y;
    __syncthreads();
    float c = cq[b * 128 + o], s = sq[b * 128 + o];
    float rot = (o < 64) ? -ybuf[o + 64] : ybuf[o - 64];
    qv[((size_t)b * HKH + h) * 128 + o] = fmaf(y, c, rot * s);
}

// ---------------- Kernel B: per-head GEMM + fused rmsnorm/rope/dot ----------
// grid = (32 m-tiles, 8 heads), 256 threads. Tile: 128 rows x 128 cols, K=256.
// Emits scores[b,h,blk] directly (k_c never materialized).
__global__ __launch_bounds__(256) void kscore_kernel(const float* __restrict__ pooled,
                                                     const float* __restrict__ Wk,
                                                     const float* __restrict__ knw,
                                                     const float* __restrict__ cosk,
                                                     const float* __restrict__ sink,
                                                     const float* __restrict__ qv,
                                                     float* __restrict__ scores) {
    __shared__ float As[128][64];   // XOR-swizzled A tile (rows x K-chunk)
    __shared__ float Ws[64][128];   // W chunk (K x N)
    int h  = blockIdx.y;
    int m0 = blockIdx.x * 128;      // global row (= b*NB + blk), 8 tiles per b
    int b  = m0 >> 10;
    int t  = threadIdx.x;
    int tc = t & 15, tr = t >> 4;   // 16 cols-groups x 16 row-groups
    int sw3 = tr & 3;

    float acc[8][8];
#pragma unroll
    for (int i = 0; i < 8; ++i)
#pragma unroll
        for (int j = 0; j < 8; ++j) acc[i][j] = 0.0f;

    for (int kk = 0; kk < 256; kk += 64) {
#pragma unroll
        for (int ii = 0; ii < 8; ++ii) {          // load A chunk: 128 x 64
            int idx = t + ii * 256;
            int lr = idx >> 4, f4 = idx & 15;
            float4 v = *(const float4*)(pooled + ((size_t)(m0 + lr) * HKH + h) * 256 + kk + f4 * 4);
            *(float4*)&As[lr][(f4 ^ (lr & 3)) << 2] = v;   // swizzle kills rd conflicts
        }
#pragma unroll
        for (int ii = 0; ii < 8; ++ii) {          // load W chunk: 64 x 128
            int idx = t + ii * 256;
            int kw = idx >> 5, f4 = idx & 31;
            float4 v = *(const float4*)(Wk + ((size_t)h * 256 + kk + kw) * 128 + f4 * 4);
            *(float4*)&Ws[kw][f4 * 4] = v;
        }
        __syncthreads();
#pragma unroll
        for (int k4 = 0; k4 < 16; ++k4) {
            float4 a4[8];
            int swc = ((k4 ^ sw3) << 2);
#pragma unroll
            for (int i = 0; i < 8; ++i) a4[i] = *(const float4*)&As[tr + 16 * i][swc];
            float4 wlo[4], whi[4];
#pragma unroll
            for (int dk = 0; dk < 4; ++dk) {
                wlo[dk] = *(const float4*)&Ws[k4 * 4 + dk][tc * 4];
                whi[dk] = *(const float4*)&Ws[k4 * 4 + dk][64 + tc * 4];
            }
#pragma unroll
            for (int dk = 0; dk < 4; ++dk) {
#pragma unroll
                for (int i = 0; i < 8; ++i) {
                    float a = (dk == 0) ? a4[i].x : (dk == 1) ? a4[i].y : (dk == 2) ? a4[i].z : a4[i].w;
                    acc[i][0] = fmaf(a, wlo[dk].x, acc[i][0]);
                    acc[i][1] = fmaf(a, wlo[dk].y, acc[i][1]);
                    acc[i][2] = fmaf(a, wlo[dk].z, acc[i][2]);
                    acc[i][3] = fmaf(a, wlo[dk].w, acc[i][3]);
                    acc[i][4] = fmaf(a, whi[dk].x, acc[i][4]);
                    acc[i][5] = fmaf(a, whi[dk].y, acc[i][5]);
                    acc[i][6] = fmaf(a, whi[dk].z, acc[i][6]);
                    acc[i][7] = fmaf(a, whi[dk].w, acc[i][7]);
                }
            }
        }
        __syncthreads();
    }

    // epilogue: rmsnorm (row) + rope + dot(qv) ; cols of this thread are
    // {4tc..4tc+3} U {64+4tc..+3} -> rope partner pairs live in-thread.
    float knlo[4], knhi[4], qlo[4], qhi[4];
    const float* qvp = qv + ((size_t)b * HKH + h) * 128;
#pragma unroll
    for (int j = 0; j < 4; ++j) {
        knlo[j] = knw[tc * 4 + j];      knhi[j] = knw[64 + tc * 4 + j];
        qlo[j]  = qvp[tc * 4 + j];      qhi[j]  = qvp[64 + tc * 4 + j];
    }
#pragma unroll
    for (int i = 0; i < 8; ++i) {
        int lr  = tr + 16 * i;
        int m   = m0 + lr;
        int blk = m & (NB - 1);
        float ss = 0.0f;
#pragma unroll
        for (int j = 0; j < 8; ++j) ss = fmaf(acc[i][j], acc[i][j], ss);
#pragma unroll
        for (int off = 1; off < 16; off <<= 1) ss += __shfl_xor(ss, off);
        float scale = rsqrtf(ss * (1.0f / 128.0f) + 1e-6f);
        const float* cb = cosk + ((size_t)b * NB + blk) * 128;
        const float* sb = sink + ((size_t)b * NB + blk) * 128;
        float part = 0.0f;
#pragma unroll
        for (int j = 0; j < 4; ++j) {
            int olo = tc * 4 + j, ohi = 64 + tc * 4 + j;
            float ylo = acc[i][j]     * scale * knlo[j];
            float yhi = acc[i][4 + j] * scale * knhi[j];
            float zlo = fmaf(ylo, cb[olo], -(yhi * sb[olo]));
            float zhi = fmaf(yhi, cb[ohi],  (ylo * sb[ohi]));
            part = fmaf(zlo, qlo[j], part);
            part = fmaf(zhi, qhi[j], part);
        }
#pragma unroll
        for (int off = 1; off < 16; off <<= 1) part += __shfl_xor(part, off);
        if (tc == 0)
            scores[((size_t)b * HKH + h) * NB + blk] = part * 0.08838834764831845f;
    }
}

// ---------------- Kernel D: top-k -> boolean mask (int32 output!) ----------
// grid = B*HK = 32 blocks, 512 threads. Bitonic-sort 1024 scores descending,
// threshold at rank bb, exact lower-index-first tie-break (matches lax.top_k).
__device__ inline bool read_mask(const void* amp, int mode, size_t idx) {
    if (mode == 1) return ((const int*)amp)[idx] != 0;
    if (mode == 2) return ((const unsigned int*)amp)[idx] != 0u;
    return ((const unsigned char*)amp)[idx] != 0;
}

__global__ __launch_bounds__(512) void topk_kernel(const float* __restrict__ scores,
                                                   const void* __restrict__ amraw,
                                                   const int* __restrict__ bbp,
                                                   int* __restrict__ out) {
    int b = blockIdx.x >> 3, h = blockIdx.x & 7;
    int t = threadIdx.x;
    __shared__ float sv[NB];
    __shared__ float ssrt[NB];
    __shared__ int  ired[4];
    __shared__ int  wred[2][8];

    if (t == 0) {
        // classify attention_mask dtype from raw bit patterns
        const unsigned int* w = (const unsigned int*)amraw;
        bool allint = true, allflt = true;
        for (int i = 0; i < 64; ++i) {
            unsigned int x = w[i];
            if (x != 0u && x != 1u) allint = false;
            if (x != 0u && x != 0x3f800000u) allflt = false;
        }
        ired[2] = allint ? 1 : (allflt ? 2 : 0);
    }
    __syncthreads();
    int mode = ired[2];
    size_t rowoff = ((size_t)b * HKH + h) * NB;
    const float* src = scores + rowoff;
    for (int s = t; s < NB; s += 512) {
        float v = read_mask(amraw, mode, rowoff + s) ? src[s] : -1e20f;
        sv[s] = v; ssrt[s] = v;
    }
    __syncthreads();
    // bitonic sort, descending
    for (int k = 2; k <= NB; k <<= 1) {
        for (int j = k >> 1; j > 0; j >>= 1) {
            int i = ((t / j) * 2 * j) + (t % j);
            int p = i + j;
            bool desc = ((i & k) == 0);
            float a = ssrt[i], c = ssrt[p];
            if (desc ? (a < c) : (a > c)) { ssrt[i] = c; ssrt[p] = a; }
            __syncthreads();
        }
    }
    int bb = bbp[0];
    if (bb > NB) bb = NB;
    if (bb < 1)  bb = 1;
    float thr = ssrt[bb - 1];
    // counts
    int cgt = 0, cge = 0;
    for (int s = t; s < NB; s += 512) {
        if (sv[s] > thr) cgt++;
        if (sv[s] >= thr) cge++;
    }
    for (int off = 32; off > 0; off >>= 1) {
        cgt += __shfl_xor(cgt, off);
        cge += __shfl_xor(cge, off);
    }
    if ((t & 63) == 0) { wred[0][t >> 6] = cgt; wred[1][t >> 6] = cge; }
    __syncthreads();
    if (t == 0) {
        int a = 0, c = 0;
        for (int wdx = 0; wdx < 8; ++wdx) { a += wred[0][wdx]; c += wred[1][wdx]; }
        ired[0] = a; ired[1] = c;
    }
    __syncthreads();
    int count_gt = ired[0], count_ge = ired[1];
    int quota = bb - count_gt;
    int* dst = out + rowoff;
    if (count_ge - count_gt <= quota) {
        // all equal-to-threshold entries selected -> fully parallel
        for (int s = t; s < NB; s += 512) {
            bool sel = (sv[s] >= thr);
            bool am  = read_mask(amraw, mode, rowoff + s);
            dst[s] = ((sel && am) || (s == NB - 1)) ? 1 : 0;
        }
    } else {
        for (int s = t; s < NB; s += 512) {
            bool sel = (sv[s] > thr);
            bool am  = read_mask(amraw, mode, rowoff + s);
            dst[s] = ((sel && am) || (s == NB - 1)) ? 1 : 0;
        }
        __syncthreads();
        if (t == 0) {   // rare: ties straddling the rank boundary, index order
            int q = quota;
            for (int s = 0; s < NB && q > 0; ++s) {
                if (sv[s] == thr) {
                    if (read_mask(amraw, mode, rowoff + s)) dst[s] = 1;
                    q--;
                }
            }
        }
    }
}

extern "C" void kernel_launch(void* const* d_in, const int* in_sizes, int n_in,
                              void* d_out, int out_size, void* d_ws, size_t ws_size,
                              hipStream_t stream) {
    (void)in_sizes; (void)n_in; (void)out_size; (void)ws_size;
    const float* k   = (const float*)d_in[0];
    const float* q   = (const float*)d_in[1];
    const float* Wq  = (const float*)d_in[2];
    const float* Wk  = (const float*)d_in[3];
    const float* qnw = (const float*)d_in[4];
    const float* knw = (const float*)d_in[5];
    const float* cq  = (const float*)d_in[6];
    const float* sq  = (const float*)d_in[7];
    const float* ck  = (const float*)d_in[8];
    const float* sk  = (const float*)d_in[9];
    const void*  am  = d_in[10];
    const int*   bb  = (const int*)d_in[11];
    int* out = (int*)d_out;

    float* pooled = (float*)d_ws;                 // 4*1024*8*256 floats = 33.5MB
    float* qv     = pooled + (size_t)4 * 1024 * 8 * 256;
    float* scores = qv + 4 * HKH * 128;

    pool_kernel<<<4096, 256, 0, stream>>>(k, pooled);
    qproj_kernel<<<32, 128, 0, stream>>>(q, Wq, qnw, cq, sq, qv);
    dim3 gb(32, 8);
    kscore_kernel<<<gb, 256, 0, stream>>>(pooled, Wk, knw, ck, sk, qv, scores);
    topk_kernel<<<32, 512, 0, stream>>>(scores, am, bb, out);
}

// Round 3
// 286.875 us; speedup vs baseline: 1.1242x; 1.1242x over previous
//
#include <hip/hip_runtime.h>
#include <hip/hip_bf16.h>
#include <math.h>

#define NB   1024    // number of key blocks per (b)
#define HKH  8       // Hk
#define DGD  128     // Dg

typedef float f4 __attribute__((ext_vector_type(4)));

// ---------------- Kernel A: pooling (mean||max over 64 rows) ----------------
// grid = B*NB = 4096 blocks, 256 threads. Each block reads a contiguous 256KB
// segment of k; nontemporal loads (pure streaming, no reuse).
__global__ __launch_bounds__(256) void pool_kernel(const float* __restrict__ kin,
                                                   float* __restrict__ pooled) {
    int blkid = blockIdx.x;            // b*NB + blk
    int t = threadIdx.x;               // 0..255 -> float4 index within 1024-float row
    const f4* src = (const f4*)kin + (size_t)blkid * 16384 + t;
    f4 v = __builtin_nontemporal_load(src);
    f4 s = v, m = v;
#pragma unroll 8
    for (int r = 1; r < 64; ++r) {
        f4 u = __builtin_nontemporal_load(src + (size_t)r * 256);
        s.x += u.x; s.y += u.y; s.z += u.z; s.w += u.w;
        m.x = fmaxf(m.x, u.x); m.y = fmaxf(m.y, u.y);
        m.z = fmaxf(m.z, u.z); m.w = fmaxf(m.w, u.w);
    }
    int h = t >> 5;                // 32 float4 per head
    int d = (t & 31) << 2;
    float* dst = pooled + ((size_t)blkid * HKH + h) * 256 + d;
    const float inv = 1.0f / 64.0f;
    f4 mean = { s.x * inv, s.y * inv, s.z * inv, s.w * inv };
    *(f4*)dst         = mean;
    *(f4*)(dst + 128) = m;
}

// ---------------- Kernel Q: query gate projection -----------------
// grid = B*HK = 32 blocks, 512 threads (4-way K split per output dim).
__global__ __launch_bounds__(512) void qproj_kernel(const float* __restrict__ q,
                                                    const float* __restrict__ Wq,
                                                    const float* __restrict__ qnw,
                                                    const float* __restrict__ cq,
                                                    const float* __restrict__ sq,
                                                    float* __restrict__ qv) {
    int b = blockIdx.x >> 3, h = blockIdx.x & 7;
    int t = threadIdx.x;
    int o = t & 127, seg = t >> 7;
    __shared__ float qs[512];
    __shared__ float part[4][128];
    __shared__ float red[2];
    __shared__ float ybuf[128];
    qs[t] = q[(size_t)b * 4096 + (size_t)h * 512 + t];
    __syncthreads();
    const float* wqp = Wq + (size_t)h * 512 * 128 + o;
    float acc = 0.0f;
    int g0 = seg * 128;
#pragma unroll 4
    for (int gi = g0; gi < g0 + 128; ++gi)
        acc = fmaf(qs[gi], wqp[(size_t)gi * 128], acc);
    part[seg][o] = acc;
    __syncthreads();
    if (t < 128) {
        float a = part[0][o] + part[1][o] + part[2][o] + part[3][o];
        ybuf[o] = a;
        float ss = a * a;
        for (int off = 32; off > 0; off >>= 1) ss += __shfl_xor(ss, off);
        if ((o & 63) == 0) red[o >> 6] = ss;
    }
    __syncthreads();
    if (t < 128) {
        float scale = rsqrtf((red[0] + red[1]) * (1.0f / 128.0f) + 1e-6f);
        float y  = ybuf[o] * scale * qnw[o];
        int op   = (o < 64) ? o + 64 : o - 64;
        float yp = ybuf[op] * scale * qnw[op];
        float rot = (o < 64) ? -yp : yp;
        qv[((size_t)b * HKH + h) * 128 + o] =
            fmaf(y, cq[b * 128 + o], rot * sq[b * 128 + o]);
    }
}

// ---------------- Kernel B: per-head GEMM + fused rmsnorm/rope/dot ----------
// grid = (64 m-tiles, 8 heads) = 512 blocks, 256 threads. Tile: 64 rows x
// 128 cols, K=256 in 4 chunks. LDS 48KB -> 3 blocks/CU, 12 waves/CU.
__global__ __launch_bounds__(256) void kscore_kernel(const float* __restrict__ pooled,
                                                     const float* __restrict__ Wk,
                                                     const float* __restrict__ knw,
                                                     const float* __restrict__ cosk,
                                                     const float* __restrict__ sink,
                                                     const float* __restrict__ qv,
                                                     float* __restrict__ scores) {
    __shared__ float As[64][64];    // XOR-swizzled A tile (rows x K-chunk)
    __shared__ float Ws[64][128];   // W chunk (K x N)
    int h  = blockIdx.y;
    int m0 = blockIdx.x * 64;       // global row (= b*NB + blk), 16 tiles per b
    int b  = m0 >> 10;
    int t  = threadIdx.x;
    int tc = t & 15, tr = t >> 4;   // 16 col-groups x 16 row-groups
    int sw3 = tr & 3;

    float acc[4][8];
#pragma unroll
    for (int i = 0; i < 4; ++i)
#pragma unroll
        for (int j = 0; j < 8; ++j) acc[i][j] = 0.0f;

    for (int kk = 0; kk < 256; kk += 64) {
#pragma unroll
        for (int ii = 0; ii < 4; ++ii) {          // load A chunk: 64 x 64
            int idx = t + ii * 256;
            int lr = idx >> 4, f4i = idx & 15;
            f4 v = *(const f4*)(pooled + ((size_t)(m0 + lr) * HKH + h) * 256 + kk + f4i * 4);
            *(f4*)&As[lr][(f4i ^ (lr & 3)) << 2] = v;   // swizzle kills rd conflicts
        }
#pragma unroll
        for (int ii = 0; ii < 8; ++ii) {          // load W chunk: 64 x 128
            int idx = t + ii * 256;
            int kw = idx >> 5, f4i = idx & 31;
            f4 v = *(const f4*)(Wk + ((size_t)h * 256 + kk + kw) * 128 + f4i * 4);
            *(f4*)&Ws[kw][f4i * 4] = v;
        }
        __syncthreads();
#pragma unroll
        for (int k4 = 0; k4 < 16; ++k4) {
            f4 a4[4];
            int swc = ((k4 ^ sw3) << 2);
#pragma unroll
            for (int i = 0; i < 4; ++i) a4[i] = *(const f4*)&As[tr + 16 * i][swc];
            f4 wlo[4], whi[4];
#pragma unroll
            for (int dk = 0; dk < 4; ++dk) {
                wlo[dk] = *(const f4*)&Ws[k4 * 4 + dk][tc * 4];
                whi[dk] = *(const f4*)&Ws[k4 * 4 + dk][64 + tc * 4];
            }
#pragma unroll
            for (int dk = 0; dk < 4; ++dk) {
#pragma unroll
                for (int i = 0; i < 4; ++i) {
                    float a = (dk == 0) ? a4[i].x : (dk == 1) ? a4[i].y : (dk == 2) ? a4[i].z : a4[i].w;
                    acc[i][0] = fmaf(a, wlo[dk].x, acc[i][0]);
                    acc[i][1] = fmaf(a, wlo[dk].y, acc[i][1]);
                    acc[i][2] = fmaf(a, wlo[dk].z, acc[i][2]);
                    acc[i][3] = fmaf(a, wlo[dk].w, acc[i][3]);
                    acc[i][4] = fmaf(a, whi[dk].x, acc[i][4]);
                    acc[i][5] = fmaf(a, whi[dk].y, acc[i][5]);
                    acc[i][6] = fmaf(a, whi[dk].z, acc[i][6]);
                    acc[i][7] = fmaf(a, whi[dk].w, acc[i][7]);
                }
            }
        }
        __syncthreads();
    }

    // epilogue: rmsnorm (row) + rope + dot(qv); cols of this thread are
    // {4tc..4tc+3} U {64+4tc..+3} -> rope partner pairs live in-thread.
    float knlo[4], knhi[4], qlo[4], qhi[4];
    const float* qvp = qv + ((size_t)b * HKH + h) * 128;
#pragma unroll
    for (int j = 0; j < 4; ++j) {
        knlo[j] = knw[tc * 4 + j];      knhi[j] = knw[64 + tc * 4 + j];
        qlo[j]  = qvp[tc * 4 + j];      qhi[j]  = qvp[64 + tc * 4 + j];
    }
#pragma unroll
    for (int i = 0; i < 4; ++i) {
        int lr  = tr + 16 * i;
        int m   = m0 + lr;
        int blk = m & (NB - 1);
        float ss = 0.0f;
#pragma unroll
        for (int j = 0; j < 8; ++j) ss = fmaf(acc[i][j], acc[i][j], ss);
#pragma unroll
        for (int off = 1; off < 16; off <<= 1) ss += __shfl_xor(ss, off);
        float scale = rsqrtf(ss * (1.0f / 128.0f) + 1e-6f);
        const float* cb = cosk + ((size_t)b * NB + blk) * 128;
        const float* sb = sink + ((size_t)b * NB + blk) * 128;
        float part = 0.0f;
#pragma unroll
        for (int j = 0; j < 4; ++j) {
            int olo = tc * 4 + j, ohi = 64 + tc * 4 + j;
            float ylo = acc[i][j]     * scale * knlo[j];
            float yhi = acc[i][4 + j] * scale * knhi[j];
            float zlo = fmaf(ylo, cb[olo], -(yhi * sb[olo]));
            float zhi = fmaf(yhi, cb[ohi],  (ylo * sb[ohi]));
            part = fmaf(zlo, qlo[j], part);
            part = fmaf(zhi, qhi[j], part);
        }
#pragma unroll
        for (int off = 1; off < 16; off <<= 1) part += __shfl_xor(part, off);
        if (tc == 0)
            scores[((size_t)b * HKH + h) * NB + blk] = part * 0.08838834764831845f;
    }
}

// ---------------- Kernel D: rank-by-counting top-k -> int32 mask ----------
// grid = B*HK = 32 blocks, 512 threads, 2 elements/thread. Element selected
// iff (#greater + #equal-at-lower-index) < bb — exactly lax.top_k's stable
// lower-index-first tie-break. One barrier, no sort.
__device__ inline bool read_mask(const void* amp, int mode, size_t idx) {
    if (mode == 1) return ((const int*)amp)[idx] != 0;
    if (mode == 2) return ((const unsigned int*)amp)[idx] != 0u;
    return ((const unsigned char*)amp)[idx] != 0;
}

__global__ __launch_bounds__(512) void topk_kernel(const float* __restrict__ scores,
                                                   const void* __restrict__ amraw,
                                                   const int* __restrict__ bbp,
                                                   int* __restrict__ out) {
    int b = blockIdx.x >> 3, h = blockIdx.x & 7;
    int t = threadIdx.x;
    __shared__ float sv[NB];
    __shared__ int mode_sh;

    if (t == 0) {
        // classify attention_mask dtype from raw bit patterns
        const unsigned int* w = (const unsigned int*)amraw;
        bool allint = true, allflt = true;
        for (int i = 0; i < 64; ++i) {
            unsigned int x = w[i];
            if (x != 0u && x != 1u) allint = false;
            if (x != 0u && x != 0x3f800000u) allflt = false;
        }
        mode_sh = allint ? 1 : (allflt ? 2 : 0);
    }
    __syncthreads();
    int mode = mode_sh;
    size_t rowoff = ((size_t)b * HKH + h) * NB;
    const float* src = scores + rowoff;
    for (int s = t; s < NB; s += 512)
        sv[s] = read_mask(amraw, mode, rowoff + s) ? src[s] : -1e20f;
    __syncthreads();

    int bb = bbp[0];
    if (bb > NB) bb = NB;
    if (bb < 1)  bb = 1;

    int e0 = t, e1 = t + 512;
    float v0 = sv[e0], v1 = sv[e1];
    int r0 = 0, r1 = 0;   // rank = #gt + #eq-at-lower-index
#pragma unroll 4
    for (int j4 = 0; j4 < 256; ++j4) {
        f4 w = *(const f4*)&sv[j4 * 4];
        int jb = j4 * 4;
        r0 += (w.x > v0) + (w.y > v0) + (w.z > v0) + (w.w > v0);
        r1 += (w.x > v1) + (w.y > v1) + (w.z > v1) + (w.w > v1);
        r0 += (w.x == v0 && jb + 0 < e0) + (w.y == v0 && jb + 1 < e0)
            + (w.z == v0 && jb + 2 < e0) + (w.w == v0 && jb + 3 < e0);
        r1 += (w.x == v1 && jb + 0 < e1) + (w.y == v1 && jb + 1 < e1)
            + (w.z == v1 && jb + 2 < e1) + (w.w == v1 && jb + 3 < e1);
    }
    int* dst = out + rowoff;
    bool am0 = read_mask(amraw, mode, rowoff + e0);
    bool am1 = read_mask(amraw, mode, rowoff + e1);
    dst[e0] = ((r0 < bb && am0)) ? 1 : 0;
    dst[e1] = ((r1 < bb && am1) || (e1 == NB - 1)) ? 1 : 0;
}

extern "C" void kernel_launch(void* const* d_in, const int* in_sizes, int n_in,
                              void* d_out, int out_size, void* d_ws, size_t ws_size,
                              hipStream_t stream) {
    (void)in_sizes; (void)n_in; (void)out_size; (void)ws_size;
    const float* k   = (const float*)d_in[0];
    const float* q   = (const float*)d_in[1];
    const float* Wq  = (const float*)d_in[2];
    const float* Wk  = (const float*)d_in[3];
    const float* qnw = (const float*)d_in[4];
    const float* knw = (const float*)d_in[5];
    const float* cq  = (const float*)d_in[6];
    const float* sq  = (const float*)d_in[7];
    const float* ck  = (const float*)d_in[8];
    const float* sk  = (const float*)d_in[9];
    const void*  am  = d_in[10];
    const int*   bb  = (const int*)d_in[11];
    int* out = (int*)d_out;

    float* pooled = (float*)d_ws;                 // 4*1024*8*256 floats = 33.5MB
    float* qv     = pooled + (size_t)4 * 1024 * 8 * 256;
    float* scores = qv + 4 * HKH * 128;

    pool_kernel<<<4096, 256, 0, stream>>>(k, pooled);
    qproj_kernel<<<32, 512, 0, stream>>>(q, Wq, qnw, cq, sq, qv);
    dim3 gb(64, 8);
    kscore_kernel<<<gb, 256, 0, stream>>>(pooled, Wk, knw, ck, sk, qv, scores);
    topk_kernel<<<32, 512, 0, stream>>>(scores, am, bb, out);
}

// Round 4
// 264.155 us; speedup vs baseline: 1.2209x; 1.0860x over previous
//
#include <hip/hip_runtime.h>
#include <hip/hip_bf16.h>
#include <math.h>

#define NB   1024    // key blocks per batch
#define HKH  8       // Hk

typedef float f4 __attribute__((ext_vector_type(4)));

// ---------------- Kernel Q: query gate projection -----------------
// grid = B*HK = 32 blocks, 512 threads (4-way K split per output dim).
__global__ __launch_bounds__(512) void qproj_kernel(const float* __restrict__ q,
                                                    const float* __restrict__ Wq,
                                                    const float* __restrict__ qnw,
                                                    const float* __restrict__ cq,
                                                    const float* __restrict__ sq,
                                                    float* __restrict__ qv) {
    int b = blockIdx.x >> 3, h = blockIdx.x & 7;
    int t = threadIdx.x;
    int o = t & 127, seg = t >> 7;
    __shared__ float qs[512];
    __shared__ float part[4][128];
    __shared__ float red[2];
    __shared__ float ybuf[128];
    qs[t] = q[(size_t)b * 4096 + (size_t)h * 512 + t];
    __syncthreads();
    const float* wqp = Wq + (size_t)h * 512 * 128 + o;
    float acc = 0.0f;
    int g0 = seg * 128;
#pragma unroll 4
    for (int gi = g0; gi < g0 + 128; ++gi)
        acc = fmaf(qs[gi], wqp[(size_t)gi * 128], acc);
    part[seg][o] = acc;
    __syncthreads();
    if (t < 128) {
        float a = part[0][o] + part[1][o] + part[2][o] + part[3][o];
        ybuf[o] = a;
        float ss = a * a;
        for (int off = 32; off > 0; off >>= 1) ss += __shfl_xor(ss, off);
        if ((o & 63) == 0) red[o >> 6] = ss;
    }
    __syncthreads();
    if (t < 128) {
        float scale = rsqrtf((red[0] + red[1]) * (1.0f / 128.0f) + 1e-6f);
        float y  = ybuf[o] * scale * qnw[o];
        int op   = (o < 64) ? o + 64 : o - 64;
        float yp = ybuf[op] * scale * qnw[op];
        float rot = (o < 64) ? -yp : yp;
        qv[((size_t)b * HKH + h) * 128 + o] =
            fmaf(y, cq[b * 128 + o], rot * sq[b * 128 + o]);
    }
}

// ---------------- Fused kernel: pool + project + rmsnorm + rope + dot -------
// grid = B(4) * H(8) * TILES(64) = 2048 wg, 256 threads.
// Each wg: stream 16 key-blocks' head-slice (1024 rows x 512B), pool in regs
// (half-wave owns 2 blocks -> no reduction), transpose into LDS At[256][17],
// then GEMM 16x128 x K=256 vs LDS-staged Wk chunks, fused epilogue -> scores.
__global__ __launch_bounds__(256) void fused_kernel(const float* __restrict__ kin,
                                                    const float* __restrict__ Wk,
                                                    const float* __restrict__ knw,
                                                    const float* __restrict__ cosk,
                                                    const float* __restrict__ sink,
                                                    const float* __restrict__ qv,
                                                    float* __restrict__ scores) {
    __shared__ float At[256][17];   // transposed A tile, +1 pad (conflict-free reads)
    __shared__ float Ws[64][128];   // Wk K-chunk
    int wg   = blockIdx.x;
    int tile = wg & 63;             // 16-block tile within b
    int h    = (wg >> 6) & 7;
    int b    = wg >> 9;
    int t    = threadIdx.x;

    // ---- Phase 1: pooling (mean||max over 64 rows per block) ----
    {
        int f4lane = t & 31;        // f4-column within the 128-float head slice
        int halfw  = t >> 5;        // half-wave id 0..7, owns blocks 2*halfw(+1)
        const float inv = 1.0f / 64.0f;
#pragma unroll
        for (int bi = 0; bi < 2; ++bi) {
            int blk = halfw * 2 + bi;                 // local block 0..15
            size_t s0 = (size_t)b * 65536 + ((size_t)tile * 16 + blk) * 64;
            const f4* src = (const f4*)(kin + s0 * 1024 + (size_t)h * 128) + f4lane;
            f4 v = __builtin_nontemporal_load(src);
            f4 s = v, m = v;
#pragma unroll 8
            for (int r = 1; r < 64; ++r) {
                f4 u = __builtin_nontemporal_load(src + (size_t)r * 256);
                s += u;
                m.x = fmaxf(m.x, u.x); m.y = fmaxf(m.y, u.y);
                m.z = fmaxf(m.z, u.z); m.w = fmaxf(m.w, u.w);
            }
            int k0 = f4lane * 4;
            At[k0 + 0][blk] = s.x * inv; At[k0 + 1][blk] = s.y * inv;
            At[k0 + 2][blk] = s.z * inv; At[k0 + 3][blk] = s.w * inv;
            At[128 + k0 + 0][blk] = m.x; At[128 + k0 + 1][blk] = m.y;
            At[128 + k0 + 2][blk] = m.z; At[128 + k0 + 3][blk] = m.w;
        }
    }

    // ---- Phase 2: GEMM 16x128, K=256 in 4 chunks ----
    int tc = t & 15, tr = t >> 4;   // thread = (row tr, col-group tc)
    float acc[8];
#pragma unroll
    for (int j = 0; j < 8; ++j) acc[j] = 0.0f;

    for (int kk = 0; kk < 256; kk += 64) {
        __syncthreads();            // At ready (1st iter) / Ws consumed (rest)
#pragma unroll
        for (int ii = 0; ii < 8; ++ii) {          // stage Ws chunk: 64 x 128
            int idx = t + ii * 256;
            int kw = idx >> 5, c4 = idx & 31;
            *(f4*)&Ws[kw][c4 * 4] =
                *(const f4*)(Wk + ((size_t)h * 256 + kk + kw) * 128 + c4 * 4);
        }
        __syncthreads();
#pragma unroll
        for (int k = 0; k < 64; ++k) {
            float a = At[kk + k][tr];
            f4 wlo = *(const f4*)&Ws[k][tc * 4];
            f4 whi = *(const f4*)&Ws[k][64 + tc * 4];
            acc[0] = fmaf(a, wlo.x, acc[0]);
            acc[1] = fmaf(a, wlo.y, acc[1]);
            acc[2] = fmaf(a, wlo.z, acc[2]);
            acc[3] = fmaf(a, wlo.w, acc[3]);
            acc[4] = fmaf(a, whi.x, acc[4]);
            acc[5] = fmaf(a, whi.y, acc[5]);
            acc[6] = fmaf(a, whi.z, acc[6]);
            acc[7] = fmaf(a, whi.w, acc[7]);
        }
    }

    // ---- Epilogue: rmsnorm (row) + rope + dot(qv); rope pairs in-thread ----
    int blkg = tile * 16 + tr;      // block index within b
    float ss = 0.0f;
#pragma unroll
    for (int j = 0; j < 8; ++j) ss = fmaf(acc[j], acc[j], ss);
#pragma unroll
    for (int off = 1; off < 16; off <<= 1) ss += __shfl_xor(ss, off);
    float scale = rsqrtf(ss * (1.0f / 128.0f) + 1e-6f);
    const float* cb  = cosk + ((size_t)b * NB + blkg) * 128;
    const float* sb  = sink + ((size_t)b * NB + blkg) * 128;
    const float* qvp = qv + ((size_t)b * HKH + h) * 128;
    float part = 0.0f;
#pragma unroll
    for (int j = 0; j < 4; ++j) {
        int olo = tc * 4 + j, ohi = 64 + olo;
        float ylo = acc[j]     * scale * knw[olo];
        float yhi = acc[4 + j] * scale * knw[ohi];
        float zlo = fmaf(ylo, cb[olo], -(yhi * sb[olo]));
        float zhi = fmaf(yhi, cb[ohi],  ylo * sb[ohi]);
        part = fmaf(zlo, qvp[olo], part);
        part = fmaf(zhi, qvp[ohi], part);
    }
#pragma unroll
    for (int off = 1; off < 16; off <<= 1) part += __shfl_xor(part, off);
    if (tc == 0)
        scores[((size_t)b * HKH + h) * NB + blkg] = part * 0.08838834764831845f;
}

// ---------------- Kernel D: rank-by-counting top-k -> int32 mask ----------
__device__ inline bool read_mask(const void* amp, int mode, size_t idx) {
    if (mode == 1) return ((const int*)amp)[idx] != 0;
    if (mode == 2) return ((const unsigned int*)amp)[idx] != 0u;
    return ((const unsigned char*)amp)[idx] != 0;
}

__global__ __launch_bounds__(512) void topk_kernel(const float* __restrict__ scores,
                                                   const void* __restrict__ amraw,
                                                   const int* __restrict__ bbp,
                                                   int* __restrict__ out) {
    int b = blockIdx.x >> 3, h = blockIdx.x & 7;
    int t = threadIdx.x;
    __shared__ float sv[NB];
    __shared__ int mode_sh;

    if (t == 0) {
        // classify attention_mask dtype from raw bit patterns
        const unsigned int* w = (const unsigned int*)amraw;
        bool allint = true, allflt = true;
        for (int i = 0; i < 64; ++i) {
            unsigned int x = w[i];
            if (x != 0u && x != 1u) allint = false;
            if (x != 0u && x != 0x3f800000u) allflt = false;
        }
        mode_sh = allint ? 1 : (allflt ? 2 : 0);
    }
    __syncthreads();
    int mode = mode_sh;
    size_t rowoff = ((size_t)b * HKH + h) * NB;
    const float* src = scores + rowoff;
    for (int s = t; s < NB; s += 512)
        sv[s] = read_mask(amraw, mode, rowoff + s) ? src[s] : -1e20f;
    __syncthreads();

    int bb = bbp[0];
    if (bb > NB) bb = NB;
    if (bb < 1)  bb = 1;

    int e0 = t, e1 = t + 512;
    float v0 = sv[e0], v1 = sv[e1];
    int r0 = 0, r1 = 0;   // rank = #gt + #eq-at-lower-index
#pragma unroll 4
    for (int j4 = 0; j4 < 256; ++j4) {
        f4 w = *(const f4*)&sv[j4 * 4];
        int jb = j4 * 4;
        r0 += (w.x > v0) + (w.y > v0) + (w.z > v0) + (w.w > v0);
        r1 += (w.x > v1) + (w.y > v1) + (w.z > v1) + (w.w > v1);
        r0 += (w.x == v0 && jb + 0 < e0) + (w.y == v0 && jb + 1 < e0)
            + (w.z == v0 && jb + 2 < e0) + (w.w == v0 && jb + 3 < e0);
        r1 += (w.x == v1 && jb + 0 < e1) + (w.y == v1 && jb + 1 < e1)
            + (w.z == v1 && jb + 2 < e1) + (w.w == v1 && jb + 3 < e1);
    }
    int* dst = out + rowoff;
    bool am0 = read_mask(amraw, mode, rowoff + e0);
    bool am1 = read_mask(amraw, mode, rowoff + e1);
    dst[e0] = ((r0 < bb && am0)) ? 1 : 0;
    dst[e1] = ((r1 < bb && am1) || (e1 == NB - 1)) ? 1 : 0;
}

extern "C" void kernel_launch(void* const* d_in, const int* in_sizes, int n_in,
                              void* d_out, int out_size, void* d_ws, size_t ws_size,
                              hipStream_t stream) {
    (void)in_sizes; (void)n_in; (void)out_size; (void)ws_size;
    const float* k   = (const float*)d_in[0];
    const float* q   = (const float*)d_in[1];
    const float* Wq  = (const float*)d_in[2];
    const float* Wk  = (const float*)d_in[3];
    const float* qnw = (const float*)d_in[4];
    const float* knw = (const float*)d_in[5];
    const float* cq  = (const float*)d_in[6];
    const float* sq  = (const float*)d_in[7];
    const float* ck  = (const float*)d_in[8];
    const float* sk  = (const float*)d_in[9];
    const void*  am  = d_in[10];
    const int*   bb  = (const int*)d_in[11];
    int* out = (int*)d_out;

    float* qv     = (float*)d_ws;                         // 4*8*128 floats
    float* scores = qv + 4 * HKH * 128;                   // 4*8*1024 floats

    qproj_kernel<<<32, 512, 0, stream>>>(q, Wq, qnw, cq, sq, qv);
    fused_kernel<<<2048, 256, 0, stream>>>(k, Wk, knw, ck, sk, qv, scores);
    topk_kernel<<<32, 512, 0, stream>>>(scores, am, bb, out);
}